// Round 9
// baseline (132.009 us; speedup 1.0000x reference)
//
#include <hip/hip_runtime.h>
#include <hip/hip_bf16.h>

typedef __attribute__((ext_vector_type(8))) short bf16x8;
typedef __attribute__((ext_vector_type(4))) float f32x4;

#define B    4
#define CIN  128
#define COUT 256
#define H    256
#define W    256
#define HW   (H * W)
#define ROWS 2           // output rows per block
#define PXW  256         // FULL-WIDTH strip: no W-halo at all

__device__ __forceinline__ unsigned short f2bf(float f) {
  unsigned int u = __builtin_bit_cast(unsigned int, f);
  u += 0x7fff + ((u >> 16) & 1);
  return (unsigned short)(u >> 16);
}

__global__ void cvt_wpw(const float* __restrict__ w, unsigned short* __restrict__ o) {
  int i = blockIdx.x * 256 + threadIdx.x;
  if (i < COUT * CIN) o[i] = f2bf(w[i]);
}

// 16-px row fragment + 1-px halos
struct R16 { f32x4 v0, v1, v2, v3; float L, R; };

__device__ __forceinline__ float rg(const R16& r, int j) {
  // j in [-1,16]; constant after unroll
  if (j < 0)  return r.L;
  if (j < 4)  return r.v0[j & 3];
  if (j < 8)  return r.v1[j & 3];
  if (j < 12) return r.v2[j & 3];
  if (j < 16) return r.v3[j & 3];
  return r.R;
}

__device__ __forceinline__ R16 lrow(const float* xr, int px0, bool pL, bool pR) {
  R16 r;
  r.v0 = *(const f32x4*)(xr + px0);
  r.v1 = *(const f32x4*)(xr + px0 + 4);
  r.v2 = *(const f32x4*)(xr + px0 + 8);
  r.v3 = *(const f32x4*)(xr + px0 + 12);
  r.L = pL ? xr[px0 - 1] : 0.f;
  r.R = pR ? xr[px0 + 16] : 0.f;
  return r;
}

__device__ __forceinline__ R16 zrow() {
  R16 r; r.L = r.R = 0.f;
  r.v0 = r.v1 = r.v2 = r.v3 = (f32x4){0.f,0.f,0.f,0.f};
  return r;
}

// LDS y layout: La = r*65536 + px*256 + ci*2 (bytes); 2 x 256 x 128 bf16 = 128 KB.
// swizzle: XOR granule bits 4-6 with (px&7)^((px>>3)&7):
//   dw u16 writes (4 ci-pairs x 16 pxg per wave) -> 32 banks, 2 lanes each (free)
//   GEMM b128 reads -> 8 lanes/granule-column = the b128 floor
__device__ __forceinline__ unsigned swz(unsigned La) {
  unsigned g = ((La >> 8) & 7) ^ ((La >> 11) & 7);
  return La ^ (g << 4);
}

// ---------------------------------------------------------------------------
// Fused dw3x3 + pw GEMM. Block = 2 rows x 256 px (full W) x 128 ci.
// 1024 thr (16 waves), 128 KB LDS, 1 block/CU, ONE barrier.
// Fetch amp = 2.0 BY CONSTRUCTION (4 rows read / 2 computed, no W-halo,
// no L2-persistence reliance; register window holds all 4 rows per ci).
// Grid 512 = xcd(8) x [hcl(16) x b(4)]: each XCD owns 16 consecutive h-chunks
// concurrently -> vertical halo rows may L2-hit (upside, not assumed).
// dw: thread = 2 ci x 16 px, ci processed sequentially (VGPR cap 128).
// pw: 16 waves = 8 co-groups x 2 px-halves; wave tile 32co x 128px,
//     MFMA 16x16x32 bf16, K=128 from LDS; acc[2][8] reset per row.
// ---------------------------------------------------------------------------
__global__ __launch_bounds__(1024, 4) void fused_kernel(
    const float* __restrict__ x, const float* __restrict__ wdw,
    const unsigned short* __restrict__ wb, float* __restrict__ out)
{
  int bid = blockIdx.x;
  int xcd = bid & 7;
  int q   = bid >> 3;          // 0..63
  int hcl = q & 15;
  int b   = q >> 4;            // 0..3
  int hc  = xcd * 16 + hcl;    // 0..127
  int hBase = hc * ROWS;       // 0..254

  int t = threadIdx.x;
  int c   = t >> 4;            // 0..63 : ci-pair
  int pxg = t & 15;            // 0..15 : 16 px each
  int ci0 = c * 2;
  int px0 = pxg * 16;
  bool pL = px0 > 0, pR = px0 + 16 < W;

  __shared__ __align__(16) char yb[ROWS * PXW * CIN * 2];   // 128 KB

  float w2[2][9];
#pragma unroll
  for (int cc = 0; cc < 2; ++cc)
#pragma unroll
    for (int k = 0; k < 9; ++k) w2[cc][k] = wdw[(ci0 + cc) * 9 + k];

  // ---- dw phase: per ci, load 4-row register window, emit 2 rows ----
#pragma unroll
  for (int cc = 0; cc < 2; ++cc) {
    int ci = ci0 + cc;
    const float* xc = x + ((size_t)b * CIN + ci) * HW;

    R16 A  = (hBase > 0) ? lrow(xc + (size_t)(hBase - 1) * W, px0, pL, pR) : zrow();
    R16 Bv = lrow(xc + (size_t)hBase * W, px0, pL, pR);
    R16 C  = lrow(xc + (size_t)(hBase + 1) * W, px0, pL, pR);     // hBase+1 <= 255
    R16 D  = (hBase + 2 < H) ? lrow(xc + (size_t)(hBase + 2) * W, px0, pL, pR) : zrow();

#pragma unroll
    for (int r = 0; r < 2; ++r) {
      const R16& Ra = (r == 0) ? A  : Bv;
      const R16& Rb = (r == 0) ? Bv : C;
      const R16& Rc = (r == 0) ? C  : D;
      const float* wr = w2[cc];
#pragma unroll
      for (int j = 0; j < 16; ++j) {
        float a =
          rg(Ra,j-1)*wr[0] + rg(Ra,j)*wr[1] + rg(Ra,j+1)*wr[2] +
          rg(Rb,j-1)*wr[3] + rg(Rb,j)*wr[4] + rg(Rb,j+1)*wr[5] +
          rg(Rc,j-1)*wr[6] + rg(Rc,j)*wr[7] + rg(Rc,j+1)*wr[8];
        unsigned La = (unsigned)r * 65536u + (unsigned)(px0 + j) * 256u + (unsigned)ci * 2u;
        *(unsigned short*)(yb + swz(La)) = f2bf(a);
      }
    }
  }

  // ---- GEMM phase ----
  int wave = t >> 6, l = t & 63;
  int l15 = l & 15, lg = l >> 4;
  int coBase = (wave >> 1) * 32;     // 8 co-groups of 32
  int pxBase = (wave & 1) * 128;     // 2 px-halves of 128

  bf16x8 Af[2][4];                   // issued just before barrier
#pragma unroll
  for (int m = 0; m < 2; ++m)
#pragma unroll
    for (int kk = 0; kk < 4; ++kk)
      Af[m][kk] = *(const bf16x8*)(wb + (coBase + m * 16 + l15) * CIN + kk * 32 + lg * 8);

  __syncthreads();

  float* ob = out + (size_t)b * COUT * HW;

#pragma unroll
  for (int r = 0; r < 2; ++r) {
    f32x4 acc[2][8];
#pragma unroll
    for (int m = 0; m < 2; ++m)
#pragma unroll
      for (int n = 0; n < 8; ++n) acc[m][n] = (f32x4){0.f,0.f,0.f,0.f};

#pragma unroll
    for (int n = 0; n < 8; ++n) {
      bf16x8 Bf[4];
#pragma unroll
      for (int kk = 0; kk < 4; ++kk) {
        unsigned La = (unsigned)r * 65536u + (unsigned)(pxBase + n * 16 + l15) * 256u
                    + (unsigned)(kk * 32 + lg * 8) * 2u;
        Bf[kk] = *(const bf16x8*)(yb + swz(La));
      }
#pragma unroll
      for (int m = 0; m < 2; ++m)
#pragma unroll
        for (int kk = 0; kk < 4; ++kk)
          acc[m][n] = __builtin_amdgcn_mfma_f32_16x16x32_bf16(Af[m][kk], Bf[kk], acc[m][n], 0, 0, 0);
    }

    float* orow = ob + (size_t)(hBase + r) * W;
#pragma unroll
    for (int m = 0; m < 2; ++m)
#pragma unroll
      for (int n = 0; n < 8; ++n)
#pragma unroll
        for (int rr = 0; rr < 4; ++rr)
          orow[(size_t)(coBase + m * 16 + lg * 4 + rr) * HW + pxBase + n * 16 + l15] = acc[m][n][rr];
  }
}

extern "C" void kernel_launch(void* const* d_in, const int* in_sizes, int n_in,
                              void* d_out, int out_size, void* d_ws, size_t ws_size,
                              hipStream_t stream) {
  const float* x   = (const float*)d_in[0];
  const float* wdw = (const float*)d_in[1];
  const float* wpw = (const float*)d_in[2];
  float* out = (float*)d_out;

  unsigned short* wbb = (unsigned short*)d_ws;   // 64 KB bf16 pw weights

  cvt_wpw<<<(COUT * CIN + 255) / 256, 256, 0, stream>>>(wpw, wbb);
  fused_kernel<<<B * (H / ROWS), 1024, 0, stream>>>(x, wdw, wbb, out);
}

// Round 10
// 107.456 us; speedup vs baseline: 1.2285x; 1.2285x over previous
//
#include <hip/hip_runtime.h>
#include <hip/hip_bf16.h>

typedef __attribute__((ext_vector_type(8))) short bf16x8;
typedef __attribute__((ext_vector_type(4))) float f32x4;

#define B    4
#define CIN  128
#define COUT 256
#define H    256
#define W    256
#define HW   (H * W)
#define ROWS 4           // output rows per block
#define PXW  128         // px strip per block

__device__ __forceinline__ unsigned short f2bf(float f) {
  unsigned int u = __builtin_bit_cast(unsigned int, f);
  u += 0x7fff + ((u >> 16) & 1);
  return (unsigned short)(u >> 16);
}

__global__ void cvt_wpw(const float* __restrict__ w, unsigned short* __restrict__ o) {
  int i = blockIdx.x * 256 + threadIdx.x;
  if (i < COUT * CIN) o[i] = f2bf(w[i]);
}

// rolling-window fragment: 8 px + halos (R8-proven geometry)
struct Row { float L; f32x4 a; f32x4 b; float R; };

__device__ __forceinline__ float rget(const Row& r, int j) {
  return (j < 0) ? r.L : (j < 4) ? r.a[j & 3] : (j < 8) ? r.b[j & 3] : r.R;
}

__device__ __forceinline__ Row load_row(const float* xr, int px0, bool pL, bool pR) {
  Row r;
  r.a = *(const f32x4*)(xr + px0);
  r.b = *(const f32x4*)(xr + px0 + 4);
  r.L = pL ? xr[px0 - 1] : 0.f;
  r.R = pR ? xr[px0 + 8] : 0.f;
  return r;
}

__device__ __forceinline__ Row zero_row() {
  Row r; r.L = r.R = 0.f;
  r.a = (f32x4){0.f,0.f,0.f,0.f};
  r.b = (f32x4){0.f,0.f,0.f,0.f};
  return r;
}

// LDS y layout: La = r*32768 + pxl*256 + ci*2 (bytes); 4 x 128 x 128 bf16 = 128 KB.
// swizzle: XOR granule bits 4-6 with (pxl&7)^((pxl>>3)&7):
//   dw u16 writes: bank = c ^ (g<<2), (c low2)x(g 3b) -> 32 banks, 2 lanes each (free)
//   GEMM b128 reads: 8 lanes/granule-quad = the b128 throughput floor
__device__ __forceinline__ unsigned swz(unsigned La) {
  unsigned g = ((La >> 8) & 7) ^ ((La >> 11) & 7);
  return La ^ (g << 4);
}

// ---------------------------------------------------------------------------
// Fused dw3x3 + pw GEMM. Block = 4 rows x 128 px x ALL 128 ci; 1024 thr
// (16 waves), 128 KB LDS, 1 block/CU, ONE barrier.
// Modeled fetch amp: h (6/4 = 1.5) x W ((4+2 lines)/4 = 1.5) = 2.25 (R8: 2.5);
// grid maps hcl 0..7 consecutively per XCD generation so vertical halo rows +
// horizontal strip-edge lines are concurrently L2-shared (upside, not assumed).
// dw: thread = 2 ci SEQUENTIAL x 8 px, rolling 3-row Row window (~70 VGPR).
// pw: 16 waves = 8 co-groups x 2 px-halves; wave tile 32co x 64px per row,
//     MFMA 16x16x32 bf16, K=128 from LDS, acc[2][4] reset per row.
// ---------------------------------------------------------------------------
__global__ __launch_bounds__(1024, 4) void fused_kernel(
    const float* __restrict__ x, const float* __restrict__ wdw,
    const unsigned short* __restrict__ wb, float* __restrict__ out)
{
  int bid = blockIdx.x;
  int xcd = bid & 7;
  int k   = bid >> 3;          // 0..63
  int hcl = k & 7;
  int sb  = k >> 3;            // 0..7
  int s   = sb & 1;
  int b   = sb >> 1;           // 0..3
  int hc  = xcd * 8 + hcl;     // 0..63
  int hBase = hc * ROWS;       // 0..252

  int t = threadIdx.x;
  int c   = t >> 4;            // 0..63 : ci-pair
  int pxg = t & 15;            // 0..15 : 8 px each
  int ci0 = c * 2;
  int px0 = s * PXW + pxg * 8; // global px
  bool pL = px0 > 0, pR = px0 + 8 < W;

  __shared__ __align__(16) char yb[ROWS * PXW * CIN * 2];   // 128 KB

  // ---- dw phase: 2 ci sequentially; rolling 3-row window over 6 rows ----
#pragma unroll
  for (int cc = 0; cc < 2; ++cc) {
    int ci = ci0 + cc;
    const float* xc = x + ((size_t)b * CIN + ci) * HW;

    float wr[9];
#pragma unroll
    for (int q = 0; q < 9; ++q) wr[q] = wdw[ci * 9 + q];

    Row A  = (hBase > 0) ? load_row(xc + (size_t)(hBase - 1) * W, px0, pL, pR) : zero_row();
    Row Bv = load_row(xc + (size_t)hBase * W, px0, pL, pR);
    Row C  = load_row(xc + (size_t)(hBase + 1) * W, px0, pL, pR);   // hBase+1 <= 253

#pragma unroll
    for (int r = 0; r < ROWS; ++r) {
      Row D;
      if (r < ROWS - 1) {
        int hh = hBase + r + 2;
        bool ok = hh < H;                   // wave-uniform (only hc=63 tail)
        D = ok ? load_row(xc + (size_t)hh * W, px0, pL, pR) : zero_row();
      }

#pragma unroll
      for (int j = 0; j < 8; ++j) {
        float a =
          rget(A, j-1)*wr[0] + rget(A, j)*wr[1] + rget(A, j+1)*wr[2] +
          rget(Bv,j-1)*wr[3] + rget(Bv,j)*wr[4] + rget(Bv,j+1)*wr[5] +
          rget(C, j-1)*wr[6] + rget(C, j)*wr[7] + rget(C, j+1)*wr[8];
        unsigned La = (unsigned)r * 32768u + (unsigned)(pxg * 8 + j) * 256u + (unsigned)ci * 2u;
        *(unsigned short*)(yb + swz(La)) = f2bf(a);
      }

      if (r < ROWS - 1) { A = Bv; Bv = C; C = D; }
    }
  }

  // ---- GEMM phase ----
  int wave = t >> 6, l = t & 63;
  int l15 = l & 15, lg = l >> 4;
  int coBase = (wave >> 1) * 32;     // 8 co-groups of 32
  int pxHalf = (wave & 1) * 64;      // 2 px-halves of 64

  bf16x8 Af[2][4];                   // issued before barrier to hide L2 latency
#pragma unroll
  for (int m = 0; m < 2; ++m)
#pragma unroll
    for (int kk = 0; kk < 4; ++kk)
      Af[m][kk] = *(const bf16x8*)(wb + (coBase + m * 16 + l15) * CIN + kk * 32 + lg * 8);

  __syncthreads();

  float* ob = out + (size_t)b * COUT * HW + s * PXW;

#pragma unroll
  for (int r = 0; r < ROWS; ++r) {
    f32x4 acc[2][4];
#pragma unroll
    for (int m = 0; m < 2; ++m)
#pragma unroll
      for (int n = 0; n < 4; ++n) acc[m][n] = (f32x4){0.f,0.f,0.f,0.f};

#pragma unroll
    for (int n = 0; n < 4; ++n) {
      bf16x8 Bf[4];
#pragma unroll
      for (int kk = 0; kk < 4; ++kk) {
        unsigned La = (unsigned)r * 32768u + (unsigned)(pxHalf + n * 16 + l15) * 256u
                    + (unsigned)(kk * 32 + lg * 8) * 2u;
        Bf[kk] = *(const bf16x8*)(yb + swz(La));
      }
#pragma unroll
      for (int m = 0; m < 2; ++m)
#pragma unroll
        for (int kk = 0; kk < 4; ++kk)
          acc[m][n] = __builtin_amdgcn_mfma_f32_16x16x32_bf16(Af[m][kk], Bf[kk], acc[m][n], 0, 0, 0);
    }

    float* orow = ob + (size_t)(hBase + r) * W;
#pragma unroll
    for (int m = 0; m < 2; ++m)
#pragma unroll
      for (int n = 0; n < 4; ++n)
#pragma unroll
        for (int rr = 0; rr < 4; ++rr)
          orow[(size_t)(coBase + m * 16 + lg * 4 + rr) * HW + pxHalf + n * 16 + l15] = acc[m][n][rr];
  }
}

extern "C" void kernel_launch(void* const* d_in, const int* in_sizes, int n_in,
                              void* d_out, int out_size, void* d_ws, size_t ws_size,
                              hipStream_t stream) {
  const float* x   = (const float*)d_in[0];
  const float* wdw = (const float*)d_in[1];
  const float* wpw = (const float*)d_in[2];
  float* out = (float*)d_out;

  unsigned short* wbb = (unsigned short*)d_ws;   // 64 KB bf16 pw weights

  cvt_wpw<<<(COUT * CIN + 255) / 256, 256, 0, stream>>>(wpw, wbb);
  fused_kernel<<<B * (H / ROWS) * (W / PXW), 1024, 0, stream>>>(x, wdw, wbb, out);
}